// Round 2
// baseline (558.065 us; speedup 1.0000x reference)
//
#include <hip/hip_runtime.h>
#include <math.h>

// Fused WaveNet-ish encoder, v7: single-accumulator split precision + deep
// load pipelining.
// - vs v6: lo-compensation folded into the SAME accumulator via
//   C += Ah*Bh + Al5*(Bh*2^-5), Al5=(w-hi)*2^5. Exactly equivalent numerics
//   (power-of-2 scales are exact), but frees 32 accumulator registers.
// - freed regs spent on explicit ks-loop pipeline: A-frags (global/L2) depth-3,
//   B-frags (LDS) depth-2 rotation -> 2 iterations of latency cover instead of 0.
// - projection ping-pong staging across two LDS buffers: 1 barrier/chunk.

#define BATCH 256
#define INCH  1024
#define HID   256
#define TLEN  128
#define CTXN  16
#define NLAY  8
#define LEAKF 0.2f
#define EPSF  1e-8f
#define SLO5  0.03125f   // 2^-5
#define SHI5  32.0f      // 2^5

typedef _Float16 f16;
typedef f16 f16x4 __attribute__((ext_vector_type(4)));
typedef f16 f16x8 __attribute__((ext_vector_type(8)));
typedef float f32x16 __attribute__((ext_vector_type(16)));

#define HT_STRIDE 264                    // halfs per row (528B, rows 16B-aligned)
#define HT_HALFS  (TLEN * HT_STRIDE)     // 33792
#define SCR_STRIDE 132
#define WS_CONV (NLAY*HID*2*HID)
#define WS_PROJ (HID*INCH)
#define WS_TOT  (WS_CONV + WS_PROJ)
#define LDS_BYTES (HT_HALFS*2*2 + (8*SCR_STRIDE + TLEN + 16)*4)   // 139968

#define MFMA32(A,B,C) __builtin_amdgcn_mfma_f32_32x32x16_f16(A,B,C,0,0,0)
// swizzle: bits from t>>3 (intra-32 groups) AND t>>5 (staging quarter groups)
#define SW(t) (((((t)>>3)&3)<<3) ^ ((((t)>>5)&3)<<4))

static __device__ __forceinline__ f16x8 mul8(f16x8 v, f16 s) {
    f16x8 r;
    #pragma unroll
    for (int i = 0; i < 8; ++i) r[i] = v[i] * s;
    return r;
}

__global__ __launch_bounds__(256)
void prep_weights(const float* __restrict__ conv_w,
                  const float* __restrict__ proj_w,
                  f16* __restrict__ wh, f16* __restrict__ wlo)
{
    const int i = blockIdx.x * blockDim.x + threadIdx.x;
    if (i >= WS_TOT) return;
    float v; int dst;
    if (i < WS_CONV) {
        // src conv_w[l][o][ii][kk] -> dst [l][o][kk][ii]
        const int kk = i & 1, ii = (i >> 1) & (HID-1), o = (i >> 9) & (HID-1), l = i >> 17;
        v = conv_w[i];
        dst = ((l*HID + o)*2 + kk)*HID + ii;
    } else {
        v = proj_w[i - WS_CONV];
        dst = i;                         // proj [o][i] after conv region
    }
    const f16 hi = (f16)v;
    wh[dst]  = hi;
    wlo[dst] = (f16)((v - (float)hi) * SHI5);
}

__global__ __launch_bounds__(1024, 4)
void wavenet7(const float* __restrict__ x,
              const f16*   __restrict__ wh,
              const f16*   __restrict__ wlo,
              const float* __restrict__ proj_b,
              const float* __restrict__ conv_b,
              const float* __restrict__ ev_w,
              const float* __restrict__ ev_b,
              const float* __restrict__ sw_w,
              const float* __restrict__ sw_b,
              float* __restrict__ out)
{
    extern __shared__ char ldsb[];
    f16*   H0   = (f16*)ldsb;                       // [128][264] swizzled, f16
    f16*   H1   = H0 + HT_HALFS;                    // second buffer (proj ping-pong)
    float* scr  = (float*)(ldsb + HT_HALFS*4);      // [8][132]
    float* attn = scr + 8*SCR_STRIDE;               // [128]
    float* redf = attn + TLEN;                      // [16]

    const int b    = blockIdx.x;
    const int tid  = threadIdx.x;
    const int lane = tid & 63;
    const int wv   = __builtin_amdgcn_readfirstlane(tid >> 6);  // 0..15
    const int mg   = wv & 7;           // o-tile: ob..ob+31
    const int ng   = wv >> 3;          // t-range: tb..tb+63 (2 n-tiles)
    const int ob   = mg << 5;
    const int tb   = ng << 6;
    const int col  = lane & 31;
    const int half = lane >> 5;

    f32x16 C[2];
    const f16x8 z8  = (f16x8)(f16)0.f;
    const f16   lo5 = (f16)SLO5;

    // ================= 1x1 projection 1024 -> 256 =================
    C[0] = (f32x16)0.f; C[1] = (f32x16)0.f;
    const f16* ph = wh  + WS_CONV;
    const f16* pl = wlo + WS_CONV;
    const float* xb = x + (size_t)b * INCH * TLEN;
    const int sr = tid >> 2, stq = tid & 3;   // stage: row in chunk, t-quarter
    float4 xv[8];

    auto LOADX = [&](int c) {
        const float* xr = xb + (size_t)(c*256 + sr) * TLEN + stq*32;
        #pragma unroll
        for (int u = 0; u < 8; ++u) xv[u] = *(const float4*)(xr + u*4);
    };
    auto STAGE = [&](f16* B) {
        #pragma unroll
        for (int u = 0; u < 8; ++u) {
            const float vv[4] = {xv[u].x, xv[u].y, xv[u].z, xv[u].w};
            #pragma unroll
            for (int e = 0; e < 4; ++e) {
                const int t = stq*32 + u*4 + e;
                const int p = t*HT_STRIDE + (((sr & ~7) ^ SW(t)) | (sr & 7));
                B[p] = (f16)vv[e];
            }
        }
    };

    LOADX(0);
    STAGE(H0);
    __syncthreads();

    #pragma unroll 1
    for (int c = 0; c < 4; ++c) {
        f16* Bt = (c & 1) ? H1 : H0;
        // --- pipelined GEMM over 16 k-steps: A depth-3 (L2), B depth-2 (LDS)
        f16x8 Ah[3], Al[3], Bf[2][2];
        const size_t abase = (size_t)(ob + col)*INCH + c*256 + half*8;
        auto LDA = [&](int ks, int s) {
            Ah[s] = *(const f16x8*)(ph + abase + ks*16);
            Al[s] = *(const f16x8*)(pl + abase + ks*16);
        };
        auto LDB = [&](int ks, int s) {
            #pragma unroll
            for (int nt = 0; nt < 2; ++nt) {
                const int t = tb + nt*32 + col;
                Bf[s][nt] = *(const f16x8*)(Bt + t*HT_STRIDE + ((ks*16 + half*8) ^ SW(t)));
            }
        };
        LDA(0,0); LDB(0,0); LDA(1,1);
        if (c < 3) LOADX(c+1);   // next x chunk: HBM latency hides under GEMM
        #pragma unroll
        for (int ks = 0; ks < 16; ++ks) {
            const int sA = ks % 3, sB = ks & 1;
            if (ks < 14) LDA(ks+2, (ks+2) % 3);
            if (ks < 15) LDB(ks+1, (ks+1) & 1);
            #pragma unroll
            for (int nt = 0; nt < 2; ++nt)
                C[nt] = MFMA32(Ah[sA], Bf[sB][nt], C[nt]);
            #pragma unroll
            for (int nt = 0; nt < 2; ++nt)
                C[nt] = MFMA32(Al[sA], mul8(Bf[sB][nt], lo5), C[nt]);
        }
        if (c < 3) {
            STAGE((c & 1) ? H0 : H1);   // other buffer: safe vs in-flight GEMM reads
            __syncthreads();
        }
    }
    // proj epilogue: h (un-normalized, + bias) -> H0.
    // H0's last readers (GEMM c=2) passed the c=2 barrier; c=3 reads H1 only.
    #pragma unroll
    for (int nt = 0; nt < 2; ++nt) {
        const int t = tb + nt*32 + col;
        const int sw = SW(t);
        #pragma unroll
        for (int q = 0; q < 4; ++q) {
            const float4 bb = *(const float4*)(proj_b + ob + 8*q + 4*half);
            const float bv[4] = {bb.x, bb.y, bb.z, bb.w};
            f16x4 h4;
            #pragma unroll
            for (int s = 0; s < 4; ++s)
                h4[s] = (f16)(C[nt][q*4+s] + bv[s]);
            *(f16x4*)(H0 + t*HT_STRIDE + ((ob + 8*q) ^ sw) + 4*half) = h4;
        }
    }
    __syncthreads();

    // ================= 8 dilated residual layers (in place in H0) ==========
    const int DIL[NLAY] = {1, 2, 4, 8, 16, 32, 64, 1};
    #pragma unroll 1
    for (int l = 0; l < NLAY; ++l) {
        const int d = DIL[l];
        C[0] = (f32x16)0.f; C[1] = (f32x16)0.f;
        const f16* wA = wh  + (size_t)l*HID*2*HID;   // [o][kk][256]
        const f16* wL = wlo + (size_t)l*HID*2*HID;
        int ro0[2], sw0[2], ro1[2], sw1[2]; bool oob1[2];
        #pragma unroll
        for (int nt = 0; nt < 2; ++nt) {
            const int t0 = tb + nt*32 + col;
            ro0[nt] = t0*HT_STRIDE; sw0[nt] = SW(t0);
            int r = t0 + d;
            oob1[nt] = r >= TLEN;
            if (oob1[nt]) r = TLEN-1;
            ro1[nt] = r*HT_STRIDE; sw1[nt] = SW(r);
        }
        const int abase = (ob + col)*2*HID + half*8;
        // --- pipelined GEMM: A (4 frags) depth-3, B (4 frags) depth-2
        f16x8 Ah0[3], Al0[3], Ah1[3], Al1[3], B0[2][2], B1[2][2];
        auto LDA = [&](int ks, int s) {
            Ah0[s] = *(const f16x8*)(wA + abase + ks*16);
            Al0[s] = *(const f16x8*)(wL + abase + ks*16);
            Ah1[s] = *(const f16x8*)(wA + abase + HID + ks*16);
            Al1[s] = *(const f16x8*)(wL + abase + HID + ks*16);
        };
        auto LDB = [&](int ks, int s) {
            const int k = ks*16 + half*8;
            #pragma unroll
            for (int nt = 0; nt < 2; ++nt) {
                B0[s][nt] = *(const f16x8*)(H0 + ro0[nt] + (k ^ sw0[nt]));
                B1[s][nt] = *(const f16x8*)(H0 + ro1[nt] + (k ^ sw1[nt]));
            }
        };
        LDA(0,0); LDB(0,0); LDA(1,1);
        #pragma unroll
        for (int ks = 0; ks < 16; ++ks) {
            const int sA = ks % 3, sB = ks & 1;
            if (ks < 14) LDA(ks+2, (ks+2) % 3);
            if (ks < 15) LDB(ks+1, (ks+1) & 1);
            #pragma unroll
            for (int nt = 0; nt < 2; ++nt)
                C[nt] = MFMA32(Ah0[sA], B0[sB][nt], C[nt]);
            #pragma unroll
            for (int nt = 0; nt < 2; ++nt)
                C[nt] = MFMA32(Al0[sA], mul8(B0[sB][nt], lo5), C[nt]);
            #pragma unroll
            for (int nt = 0; nt < 2; ++nt) {
                f16x8 Bv = B1[sB][nt];
                if (oob1[nt]) Bv = z8;
                C[nt] = MFMA32(Ah1[sA], Bv, C[nt]);
                C[nt] = MFMA32(Al1[sA], mul8(Bv, lo5), C[nt]);
            }
        }
        // ---- epilogue: bias + leaky + skip + sumsq ----
        float ps[2] = {0.f, 0.f};
        #pragma unroll
        for (int nt = 0; nt < 2; ++nt) {
            const int t = tb + nt*32 + col;
            const int sw = SW(t);
            #pragma unroll
            for (int q = 0; q < 4; ++q) {
                const float4 bb = *(const float4*)(conv_b + l*HID + ob + 8*q + 4*half);
                const float bv[4] = {bb.x, bb.y, bb.z, bb.w};
                const int p = t*HT_STRIDE + ((ob + 8*q) ^ sw) + 4*half;
                const f16x4 sh = *(const f16x4*)(H0 + p);
                #pragma unroll
                for (int s = 0; s < 4; ++s) {
                    float y = C[nt][q*4+s] + bv[s];
                    y = y > 0.f ? y : LEAKF * y;
                    const float v = y + (float)sh[s];
                    C[nt][q*4+s] = v;
                    ps[nt] = fmaf(v, v, ps[nt]);
                }
            }
        }
        ps[0] += __shfl_xor(ps[0], 32);
        ps[1] += __shfl_xor(ps[1], 32);
        if (lane < 32) {
            scr[mg*SCR_STRIDE + tb +      col] = ps[0];
            scr[mg*SCR_STRIDE + tb + 32 + col] = ps[1];
        }
        __syncthreads();   // all conv/skip reads done + scr complete
        float inv[2];
        #pragma unroll
        for (int nt = 0; nt < 2; ++nt) {
            const int t = tb + nt*32 + col;
            float s = 0.f;
            #pragma unroll
            for (int g = 0; g < 8; ++g) s += scr[g*SCR_STRIDE + t];
            inv[nt] = 1.f / (sqrtf(s) + EPSF);
        }
        #pragma unroll
        for (int nt = 0; nt < 2; ++nt) {
            const int t = tb + nt*32 + col;
            const int sw = SW(t);
            #pragma unroll
            for (int q = 0; q < 4; ++q) {
                f16x4 h4;
                #pragma unroll
                for (int s = 0; s < 4; ++s)
                    h4[s] = (f16)(C[nt][q*4+s] * inv[nt]);
                *(f16x4*)(H0 + t*HT_STRIDE + ((ob + 8*q) ^ sw) + 4*half) = h4;
            }
        }
        __syncthreads();
    }

    // ================= switch head -> relu -> argmax =================
    {
        const int t = tid & 127, og = tid >> 7;
        const int sw = SW(t);
        float s = 0.f;
        #pragma unroll
        for (int q = 0; q < 4; ++q) {
            const int grp = og*32 + q*8;
            const f16x8 hv = *(const f16x8*)(H0 + t*HT_STRIDE + (grp ^ sw));
            const float* swp = sw_w + grp;
            #pragma unroll
            for (int j = 0; j < 8; ++j)
                s = fmaf(swp[j], (float)hv[j], s);
        }
        scr[og*SCR_STRIDE + t] = s;
    }
    __syncthreads();
    if (tid < TLEN) {
        float s = sw_b[0];
        #pragma unroll
        for (int g = 0; g < 8; ++g) s += scr[g*SCR_STRIDE + tid];
        attn[tid] = fmaxf(s, 0.f);
    }
    __syncthreads();
    if (tid < 64) {
        float v = attn[lane]; int bi = lane;
        const float v2 = attn[lane + 64];
        if (v2 > v) { v = v2; bi = lane + 64; }
        #pragma unroll
        for (int off = 32; off > 0; off >>= 1) {
            const float ov = __shfl_down(v, off);
            const int   oi = __shfl_down(bi, off);
            if (ov > v || (ov == v && oi < bi)) { v = ov; bi = oi; }
        }
        if (lane == 0) { redf[0] = v; ((int*)redf)[1] = bi; }
    }
    __syncthreads();
    const float bestv = redf[0];
    const int   bidx  = ((const int*)redf)[1];
    const int   swb   = SW(bidx);

    // event head: wave wv computes ctx=wv from h[:, bidx]
    {
        float s = 0.f;
        #pragma unroll
        for (int q = 0; q < 4; ++q) {
            const int o = lane + 64*q;
            const int p = bidx*HT_STRIDE + (((o & ~7) ^ swb) | (o & 7));
            s = fmaf(ev_w[wv*HID + o], (float)H0[p], s);
        }
        #pragma unroll
        for (int off = 32; off > 0; off >>= 1) s += __shfl_down(s, off);
        if (lane == 0) out[b*CTXN + wv] = s + ev_b[wv];
    }
    if (tid < TLEN) out[BATCH*CTXN + b*TLEN + tid] = (tid == bidx) ? bestv : 0.f;
}

extern "C" void kernel_launch(void* const* d_in, const int* in_sizes, int n_in,
                              void* d_out, int out_size, void* d_ws, size_t ws_size,
                              hipStream_t stream) {
    const float* x      = (const float*)d_in[0];
    const float* proj_w = (const float*)d_in[1];
    const float* proj_b = (const float*)d_in[2];
    const float* conv_w = (const float*)d_in[3];
    const float* conv_b = (const float*)d_in[4];
    const float* ev_w   = (const float*)d_in[5];
    const float* ev_b   = (const float*)d_in[6];
    const float* sw_w   = (const float*)d_in[7];
    const float* sw_b   = (const float*)d_in[8];
    float* out = (float*)d_out;

    f16* wh  = (f16*)d_ws;
    f16* wlo = wh + WS_TOT;

    prep_weights<<<(WS_TOT + 255)/256, 256, 0, stream>>>(conv_w, proj_w, wh, wlo);

    (void)hipFuncSetAttribute((const void*)wavenet7,
                              hipFuncAttributeMaxDynamicSharedMemorySize, (int)LDS_BYTES);
    wavenet7<<<BATCH, 1024, LDS_BYTES, stream>>>(x, wh, wlo, proj_b, conv_b,
                                                 ev_w, ev_b, sw_w, sw_b, out);
}

// Round 3
// 510.033 us; speedup vs baseline: 1.0942x; 1.0942x over previous
//
#include <hip/hip_runtime.h>
#include <math.h>

// Fused WaveNet-ish encoder, v8: anti-spill build.
// Theory: v5-v7 all spilled (WRITE_SIZE 59-95 MB of scratch traffic vs 0.15 MB
// of real output) because inner-loop live sets exceeded the 128-reg budget
// (launch_bounds 1024x4). v8 keeps v7's single-accumulator math
// (C += Ah*B + Al5*(B*2^-5), 32 AGPRs) but:
//  - no xv prefetch across GEMM (32 regs freed; ~1us of exposed HBM latency)
//  - no explicit pipeline arrays (compiler schedules within unroll-2 window)
//  - #pragma unroll 2 on ks loops (caps load-hoist window ~48 regs)
//  - no runtime-indexed DIL[] array (scratch trigger): d computed arithmetically

#define BATCH 256
#define INCH  1024
#define HID   256
#define TLEN  128
#define CTXN  16
#define NLAY  8
#define LEAKF 0.2f
#define EPSF  1e-8f
#define SLO5  0.03125f   // 2^-5
#define SHI5  32.0f      // 2^5

typedef _Float16 f16;
typedef f16 f16x4 __attribute__((ext_vector_type(4)));
typedef f16 f16x8 __attribute__((ext_vector_type(8)));
typedef float f32x16 __attribute__((ext_vector_type(16)));

#define HT_STRIDE 264                    // halfs per row (528B, rows 16B-aligned)
#define HT_HALFS  (TLEN * HT_STRIDE)     // 33792
#define SCR_STRIDE 132
#define WS_CONV (NLAY*HID*2*HID)
#define WS_PROJ (HID*INCH)
#define WS_TOT  (WS_CONV + WS_PROJ)
#define LDS_BYTES (HT_HALFS*2 + (8*SCR_STRIDE + TLEN + 16)*4)   // 72384

#define MFMA32(A,B,C) __builtin_amdgcn_mfma_f32_32x32x16_f16(A,B,C,0,0,0)
// swizzle: bits from t>>3 (intra-32 groups) AND t>>5 (staging quarter groups)
#define SW(t) (((((t)>>3)&3)<<3) ^ ((((t)>>5)&3)<<4))

static __device__ __forceinline__ f16x8 mul8(f16x8 v, f16 s) {
    f16x8 r;
    #pragma unroll
    for (int i = 0; i < 8; ++i) r[i] = v[i] * s;
    return r;
}

__global__ __launch_bounds__(256)
void prep_weights(const float* __restrict__ conv_w,
                  const float* __restrict__ proj_w,
                  f16* __restrict__ wh, f16* __restrict__ wlo)
{
    const int i = blockIdx.x * blockDim.x + threadIdx.x;
    if (i >= WS_TOT) return;
    float v; int dst;
    if (i < WS_CONV) {
        // src conv_w[l][o][ii][kk] -> dst [l][o][kk][ii]
        const int kk = i & 1, ii = (i >> 1) & (HID-1), o = (i >> 9) & (HID-1), l = i >> 17;
        v = conv_w[i];
        dst = ((l*HID + o)*2 + kk)*HID + ii;
    } else {
        v = proj_w[i - WS_CONV];
        dst = i;                         // proj [o][i] after conv region
    }
    const f16 hi = (f16)v;
    wh[dst]  = hi;
    wlo[dst] = (f16)((v - (float)hi) * SHI5);
}

__global__ __launch_bounds__(1024, 4)
void wavenet8(const float* __restrict__ x,
              const f16*   __restrict__ wh,
              const f16*   __restrict__ wlo,
              const float* __restrict__ proj_b,
              const float* __restrict__ conv_b,
              const float* __restrict__ ev_w,
              const float* __restrict__ ev_b,
              const float* __restrict__ sw_w,
              const float* __restrict__ sw_b,
              float* __restrict__ out)
{
    extern __shared__ char ldsb[];
    f16*   Ht   = (f16*)ldsb;                       // [128][264] swizzled, f16
    float* scr  = (float*)(ldsb + HT_HALFS*2);      // [8][132]
    float* attn = scr + 8*SCR_STRIDE;               // [128]
    float* redf = attn + TLEN;                      // [16]

    const int b    = blockIdx.x;
    const int tid  = threadIdx.x;
    const int lane = tid & 63;
    const int wv   = __builtin_amdgcn_readfirstlane(tid >> 6);  // 0..15
    const int mg   = wv & 7;           // o-tile: ob..ob+31
    const int ng   = wv >> 3;          // t-range: tb..tb+63 (2 n-tiles)
    const int ob   = mg << 5;
    const int tb   = ng << 6;
    const int col  = lane & 31;
    const int half = lane >> 5;

    f32x16 C[2];
    const f16x8 z8  = (f16x8)(f16)0.f;
    const f16   lo5 = (f16)SLO5;

    // ================= 1x1 projection 1024 -> 256 =================
    C[0] = (f32x16)0.f; C[1] = (f32x16)0.f;
    const f16* ph = wh  + WS_CONV;
    const f16* pl = wlo + WS_CONV;
    const float* xb = x + (size_t)b * INCH * TLEN;
    const int sr = tid >> 2, stq = tid & 3;   // stage: row in chunk, t-quarter

    #pragma unroll 1
    for (int c = 0; c < 4; ++c) {
        if (c) __syncthreads();          // previous chunk's B-reads complete
        {   // load + stage (transient registers only)
            const float* xr = xb + (size_t)(c*256 + sr) * TLEN + stq*32;
            #pragma unroll
            for (int u = 0; u < 8; ++u) {
                const float4 v4 = *(const float4*)(xr + u*4);
                const float vv[4] = {v4.x, v4.y, v4.z, v4.w};
                #pragma unroll
                for (int e = 0; e < 4; ++e) {
                    const int t = stq*32 + u*4 + e;
                    const int p = t*HT_STRIDE + (((sr & ~7) ^ SW(t)) | (sr & 7));
                    Ht[p] = (f16)vv[e];
                }
            }
        }
        __syncthreads();
        #pragma unroll 2
        for (int ks = 0; ks < 16; ++ks) {
            const int kloc = ks*16 + half*8;
            const size_t ao = (size_t)(ob + col)*INCH + c*256 + kloc;
            const f16x8 Ah = *(const f16x8*)(ph + ao);
            const f16x8 Al = *(const f16x8*)(pl + ao);
            #pragma unroll
            for (int nt = 0; nt < 2; ++nt) {
                const int t = tb + nt*32 + col;
                const f16x8 Bh = *(const f16x8*)(Ht + t*HT_STRIDE + (kloc ^ SW(t)));
                C[nt] = MFMA32(Ah, Bh, C[nt]);
                C[nt] = MFMA32(Al, mul8(Bh, lo5), C[nt]);
            }
        }
    }
    __syncthreads();   // all B-reads done; Ht free for h
    #pragma unroll
    for (int nt = 0; nt < 2; ++nt) {
        const int t = tb + nt*32 + col;
        const int sw = SW(t);
        #pragma unroll
        for (int q = 0; q < 4; ++q) {
            const float4 bb = *(const float4*)(proj_b + ob + 8*q + 4*half);
            const float bv[4] = {bb.x, bb.y, bb.z, bb.w};
            f16x4 h4;
            #pragma unroll
            for (int s = 0; s < 4; ++s)
                h4[s] = (f16)(C[nt][q*4+s] + bv[s]);
            *(f16x4*)(Ht + t*HT_STRIDE + ((ob + 8*q) ^ sw) + 4*half) = h4;
        }
    }
    __syncthreads();

    // ================= 8 dilated residual layers (in place in Ht) ==========
    #pragma unroll 1
    for (int l = 0; l < NLAY; ++l) {
        const int d = (l < 7) ? (1 << l) : 1;   // 1,2,4,8,16,32,64,1 (no array!)
        C[0] = (f32x16)0.f; C[1] = (f32x16)0.f;
        const f16* wA = wh  + (size_t)l*HID*2*HID;   // [o][kk][256]
        const f16* wL = wlo + (size_t)l*HID*2*HID;
        int ro0[2], sw0[2], ro1[2], sw1[2]; bool oob1[2];
        #pragma unroll
        for (int nt = 0; nt < 2; ++nt) {
            const int t0 = tb + nt*32 + col;
            ro0[nt] = t0*HT_STRIDE; sw0[nt] = SW(t0);
            int r = t0 + d;
            oob1[nt] = r >= TLEN;
            if (oob1[nt]) r = TLEN-1;
            ro1[nt] = r*HT_STRIDE; sw1[nt] = SW(r);
        }
        const int abase = (ob + col)*2*HID + half*8;
        #pragma unroll 2
        for (int ks = 0; ks < 16; ++ks) {
            const int k = ks*16;
            {   // ---- kk = 0 ----
                const f16x8 Ah = *(const f16x8*)(wA + abase + k);
                const f16x8 Al = *(const f16x8*)(wL + abase + k);
                #pragma unroll
                for (int nt = 0; nt < 2; ++nt) {
                    const f16x8 Bh = *(const f16x8*)(Ht + ro0[nt] + ((k + half*8) ^ sw0[nt]));
                    C[nt] = MFMA32(Ah, Bh, C[nt]);
                    C[nt] = MFMA32(Al, mul8(Bh, lo5), C[nt]);
                }
            }
            {   // ---- kk = 1 (shift +d, boundary-masked) ----
                const f16x8 Ah = *(const f16x8*)(wA + abase + HID + k);
                const f16x8 Al = *(const f16x8*)(wL + abase + HID + k);
                #pragma unroll
                for (int nt = 0; nt < 2; ++nt) {
                    f16x8 Bh = *(const f16x8*)(Ht + ro1[nt] + ((k + half*8) ^ sw1[nt]));
                    if (oob1[nt]) Bh = z8;
                    C[nt] = MFMA32(Ah, Bh, C[nt]);
                    C[nt] = MFMA32(Al, mul8(Bh, lo5), C[nt]);
                }
            }
        }
        // ---- epilogue: bias + leaky + skip + sumsq ----
        float ps[2] = {0.f, 0.f};
        #pragma unroll
        for (int nt = 0; nt < 2; ++nt) {
            const int t = tb + nt*32 + col;
            const int sw = SW(t);
            #pragma unroll
            for (int q = 0; q < 4; ++q) {
                const float4 bb = *(const float4*)(conv_b + l*HID + ob + 8*q + 4*half);
                const float bv[4] = {bb.x, bb.y, bb.z, bb.w};
                const int p = t*HT_STRIDE + ((ob + 8*q) ^ sw) + 4*half;
                const f16x4 sh = *(const f16x4*)(Ht + p);
                #pragma unroll
                for (int s = 0; s < 4; ++s) {
                    float y = C[nt][q*4+s] + bv[s];
                    y = y > 0.f ? y : LEAKF * y;
                    const float v = y + (float)sh[s];
                    C[nt][q*4+s] = v;
                    ps[nt] = fmaf(v, v, ps[nt]);
                }
            }
        }
        ps[0] += __shfl_xor(ps[0], 32);
        ps[1] += __shfl_xor(ps[1], 32);
        if (lane < 32) {
            scr[mg*SCR_STRIDE + tb +      col] = ps[0];
            scr[mg*SCR_STRIDE + tb + 32 + col] = ps[1];
        }
        __syncthreads();   // all conv/skip reads done + scr complete
        float inv[2];
        #pragma unroll
        for (int nt = 0; nt < 2; ++nt) {
            const int t = tb + nt*32 + col;
            float s = 0.f;
            #pragma unroll
            for (int g = 0; g < 8; ++g) s += scr[g*SCR_STRIDE + t];
            inv[nt] = 1.f / (sqrtf(s) + EPSF);
        }
        #pragma unroll
        for (int nt = 0; nt < 2; ++nt) {
            const int t = tb + nt*32 + col;
            const int sw = SW(t);
            #pragma unroll
            for (int q = 0; q < 4; ++q) {
                f16x4 h4;
                #pragma unroll
                for (int s = 0; s < 4; ++s)
                    h4[s] = (f16)(C[nt][q*4+s] * inv[nt]);
                *(f16x4*)(Ht + t*HT_STRIDE + ((ob + 8*q) ^ sw) + 4*half) = h4;
            }
        }
        __syncthreads();
    }

    // ================= switch head -> relu -> argmax =================
    {
        const int t = tid & 127, og = tid >> 7;
        const int sw = SW(t);
        float s = 0.f;
        #pragma unroll
        for (int q = 0; q < 4; ++q) {
            const int grp = og*32 + q*8;
            const f16x8 hv = *(const f16x8*)(Ht + t*HT_STRIDE + (grp ^ sw));
            const float* swp = sw_w + grp;
            #pragma unroll
            for (int j = 0; j < 8; ++j)
                s = fmaf(swp[j], (float)hv[j], s);
        }
        scr[og*SCR_STRIDE + t] = s;
    }
    __syncthreads();
    if (tid < TLEN) {
        float s = sw_b[0];
        #pragma unroll
        for (int g = 0; g < 8; ++g) s += scr[g*SCR_STRIDE + tid];
        attn[tid] = fmaxf(s, 0.f);
    }
    __syncthreads();
    if (tid < 64) {
        float v = attn[lane]; int bi = lane;
        const float v2 = attn[lane + 64];
        if (v2 > v) { v = v2; bi = lane + 64; }
        #pragma unroll
        for (int off = 32; off > 0; off >>= 1) {
            const float ov = __shfl_down(v, off);
            const int   oi = __shfl_down(bi, off);
            if (ov > v || (ov == v && oi < bi)) { v = ov; bi = oi; }
        }
        if (lane == 0) { redf[0] = v; ((int*)redf)[1] = bi; }
    }
    __syncthreads();
    const float bestv = redf[0];
    const int   bidx  = ((const int*)redf)[1];
    const int   swb   = SW(bidx);

    // event head: wave wv computes ctx=wv from h[:, bidx]
    {
        float s = 0.f;
        #pragma unroll
        for (int q = 0; q < 4; ++q) {
            const int o = lane + 64*q;
            const int p = bidx*HT_STRIDE + (((o & ~7) ^ swb) | (o & 7));
            s = fmaf(ev_w[wv*HID + o], (float)Ht[p], s);
        }
        #pragma unroll
        for (int off = 32; off > 0; off >>= 1) s += __shfl_down(s, off);
        if (lane == 0) out[b*CTXN + wv] = s + ev_b[wv];
    }
    if (tid < TLEN) out[BATCH*CTXN + b*TLEN + tid] = (tid == bidx) ? bestv : 0.f;
}

extern "C" void kernel_launch(void* const* d_in, const int* in_sizes, int n_in,
                              void* d_out, int out_size, void* d_ws, size_t ws_size,
                              hipStream_t stream) {
    const float* x      = (const float*)d_in[0];
    const float* proj_w = (const float*)d_in[1];
    const float* proj_b = (const float*)d_in[2];
    const float* conv_w = (const float*)d_in[3];
    const float* conv_b = (const float*)d_in[4];
    const float* ev_w   = (const float*)d_in[5];
    const float* ev_b   = (const float*)d_in[6];
    const float* sw_w   = (const float*)d_in[7];
    const float* sw_b   = (const float*)d_in[8];
    float* out = (float*)d_out;

    f16* wh  = (f16*)d_ws;
    f16* wlo = wh + WS_TOT;

    prep_weights<<<(WS_TOT + 255)/256, 256, 0, stream>>>(conv_w, proj_w, wh, wlo);

    (void)hipFuncSetAttribute((const void*)wavenet8,
                              hipFuncAttributeMaxDynamicSharedMemorySize, (int)LDS_BYTES);
    wavenet8<<<BATCH, 1024, LDS_BYTES, stream>>>(x, wh, wlo, proj_b, conv_b,
                                                 ev_w, ev_b, sw_w, sw_b, out);
}